// Round 1
// baseline (57.955 us; speedup 1.0000x reference)
//
#include <hip/hip_runtime.h>

typedef _Float16 f16x8 __attribute__((ext_vector_type(8)));
typedef float f32x4 __attribute__((ext_vector_type(4)));

#define B_SZ 16384
#define C_SZ 256
#define BC (B_SZ * C_SZ)

// Pack Wu/Wg/Wa/Wd -> wsB[p][k] f16, p in [0,1024), k in [0,512).
// p = cb*256 + wv*64 + strip*16 + t  maps to  c = cb*64 + wv*16 + t, matrix=strip.
// strip 0 = Wu (K zero-padded 256..511), 1 = Wg, 2 = Wa, 3 = Wd.
__global__ __launch_bounds__(256) void pack_w(const float* __restrict__ Wu,
                                              const float* __restrict__ Wg,
                                              const float* __restrict__ Wa,
                                              const float* __restrict__ Wd,
                                              _Float16* __restrict__ wsB) {
  int tid = blockIdx.x * 256 + threadIdx.x;  // 65536 threads total
  int k0 = (tid & 63) * 8;
  int p = tid >> 6;
  int cb = p >> 8;
  int r = p & 255;
  int wv = r >> 6;
  int strip = (r >> 4) & 3;
  int t = r & 15;
  int c = cb * 64 + wv * 16 + t;
  float v[8];
  if (strip == 0) {
    if (k0 < 256) {
      const float* s = Wu + c * 256 + k0;
#pragma unroll
      for (int i = 0; i < 8; ++i) v[i] = s[i];
    } else {
#pragma unroll
      for (int i = 0; i < 8; ++i) v[i] = 0.f;
    }
  } else {
    const float* s = (strip == 1 ? Wg : (strip == 2 ? Wa : Wd)) + c * 512 + k0;
#pragma unroll
    for (int i = 0; i < 8; ++i) v[i] = s[i];
  }
  f16x8 o;
#pragma unroll
  for (int i = 0; i < 8; ++i) o[i] = (_Float16)v[i];
  *reinterpret_cast<f16x8*>(wsB + (size_t)p * 512 + k0) = o;
}

// One fused kernel: GEMM [16384,512]x[512,1024] (f16 MFMA, fp32 acc) + epilogue.
// Block: 64 rows x 256 packed cols (= 64 c-values x 4 matrices). 4 waves along N.
// Wave wv owns packed rows [wv*64, wv*64+64) = strips {u,g,a,d} x 16 c -> ni == strip.
__global__ __launch_bounds__(256, 2) void rwa_main(
    const float* __restrict__ x, const float* __restrict__ nt_,
    const float* __restrict__ dt_, const float* __restrict__ h,
    const float* __restrict__ amax_, const float* __restrict__ bu,
    const float* __restrict__ bg, const _Float16* __restrict__ wsB,
    float* __restrict__ out) {
  __shared__ __align__(16) _Float16 ldsA[2][64 * 64];    // 2 x 8 KB
  __shared__ __align__(16) _Float16 ldsB[2][256 * 64];   // 2 x 32 KB

  const int tid = threadIdx.x;
  const int lane = tid & 63;
  const int wv = tid >> 6;

  // XCD-aware swizzle: xcd = bid%8 (HW round-robin); the 4 cb-blocks of one
  // row-panel land on the same XCD -> x/h panel re-reads hit that XCD's L2.
  const int bid = blockIdx.x;
  const int xcd = bid & 7;
  const int q = bid >> 3;
  const int cb = q & 3;                 // which 64-wide c chunk
  const int rowblk = (q >> 2) * 8 + xcd;
  const int row0 = rowblk * 64;

  const int sr = tid >> 3;        // staging sub-row 0..31
  const int scf = (tid & 7) * 8;  // staging col (elements)

  f32x4 acc[4][4] = {};  // [mi][ni(strip)]

  // A tile: xh[row0..row0+64) x 64 k, f32 -> f16, XOR-swizzled LDS write.
  auto stageA = [&](int buf, int kt) {
    const float* src = (kt < 4) ? x : h;
    const int kcol = (kt & 3) * 64;
#pragma unroll
    for (int s = 0; s < 2; ++s) {
      const int r = s * 32 + sr;
      const float* sp = src + (size_t)(row0 + r) * 256 + kcol + scf;
      f32x4 a0 = *reinterpret_cast<const f32x4*>(sp);
      f32x4 a1 = *reinterpret_cast<const f32x4*>(sp + 4);
      f16x8 o;
#pragma unroll
      for (int i = 0; i < 4; ++i) { o[i] = (_Float16)a0[i]; o[4 + i] = (_Float16)a1[i]; }
      const int off = (r * 128 + scf * 2) ^ ((r & 7) << 4);
      *reinterpret_cast<f16x8*>(reinterpret_cast<char*>(&ldsA[buf][0]) + off) = o;
    }
  };

  // B tile: wsB rows [cb*256, cb*256+256) x 64 k (already f16), swizzled write.
  auto stageB = [&](int buf, int kt) {
#pragma unroll
    for (int s = 0; s < 8; ++s) {
      const int r = s * 32 + sr;
      const _Float16* sp = wsB + (size_t)(cb * 256 + r) * 512 + kt * 64 + scf;
      f16x8 vv = *reinterpret_cast<const f16x8*>(sp);
      const int off = (r * 128 + scf * 2) ^ ((r & 7) << 4);
      *reinterpret_cast<f16x8*>(reinterpret_cast<char*>(&ldsB[buf][0]) + off) = vv;
    }
  };

  stageA(0, 0);
  stageB(0, 0);
  __syncthreads();

  const int l15 = lane & 15;
  const int lg = lane >> 4;
  const int swz = (lane & 7) << 4;  // row&7 == lane&7 for all frag reads

  int buf = 0;
  for (int kt = 0; kt < 8; ++kt) {
    if (kt < 7) {  // issue next-tile staging before compute (loads fly over MFMA)
      stageA(buf ^ 1, kt + 1);
      stageB(buf ^ 1, kt + 1);
    }
    const char* pA = reinterpret_cast<const char*>(&ldsA[buf][0]);
    const char* pB = reinterpret_cast<const char*>(&ldsB[buf][0]);
    const bool doU = (kt < 4);  // Wu strip is zero-padded for k >= 256
#pragma unroll
    for (int ks = 0; ks < 2; ++ks) {
      f16x8 af[4];
#pragma unroll
      for (int mi = 0; mi < 4; ++mi) {
        const int row = mi * 16 + l15;
        af[mi] = *reinterpret_cast<const f16x8*>(
            pA + ((row * 128 + ks * 64 + lg * 16) ^ swz));
      }
      f16x8 bfr[4];
#pragma unroll
      for (int ni = 0; ni < 4; ++ni) {
        if (ni == 0 && !doU) continue;
        const int row = wv * 64 + ni * 16 + l15;
        bfr[ni] = *reinterpret_cast<const f16x8*>(
            pB + ((row * 128 + ks * 64 + lg * 16) ^ swz));
      }
#pragma unroll
      for (int ni = 0; ni < 4; ++ni) {
        if (ni == 0 && !doU) continue;
#pragma unroll
        for (int mi = 0; mi < 4; ++mi)
          acc[mi][ni] = __builtin_amdgcn_mfma_f32_16x16x32_f16(
              af[mi], bfr[ni], acc[mi][ni], 0, 0, 0);
      }
    }
    __syncthreads();
    buf ^= 1;
  }

  // Epilogue: each lane holds u,g,a,dec for the same (r,c). C/D layout:
  // col = lane&15, row = (lane>>4)*4 + reg (+ mi*16).
  const int c = cb * 64 + wv * 16 + l15;
  const float buv = bu[c];
  const float bgv = bg[c];
  const int rbase = row0 + lg * 4;
#pragma unroll
  for (int mi = 0; mi < 4; ++mi) {
#pragma unroll
    for (int rg = 0; rg < 4; ++rg) {
      const int r = rbase + mi * 16 + rg;
      const int idx = r * 256 + c;
      const float u = acc[mi][0][rg] + buv;
      const float g = acc[mi][1][rg] + bgv;
      const float a = acc[mi][2][rg];
      const float dr = acc[mi][3][rg];
      const float decay = 1.f / (1.f + __expf(-dr));
      const float e_neg = __expf(-decay);
      const float z = u * tanhf(g);
      const float am = amax_[idx];
      const float n_old = nt_[idx];
      const float d_old = dt_[idx];
      const float a_dec = am * e_neg;
      const float a_new = fmaxf(a_dec, a);
      const float ediff = __expf(am - a_new);
      const float escal = __expf(a - a_new);
      const float comm = e_neg * ediff;
      const float n_new = n_old * comm + z * escal;
      const float d_new = d_old * comm + escal;
      const float h_new = tanhf(n_new / d_new);
      out[idx] = n_new;
      out[BC + idx] = d_new;
      out[2 * BC + idx] = h_new;
      out[3 * BC + idx] = a_new;
    }
  }
}

extern "C" void kernel_launch(void* const* d_in, const int* in_sizes, int n_in,
                              void* d_out, int out_size, void* d_ws, size_t ws_size,
                              hipStream_t stream) {
  const float* x_t    = (const float*)d_in[0];
  const float* n_t    = (const float*)d_in[1];
  const float* d_t    = (const float*)d_in[2];
  const float* h_t    = (const float*)d_in[3];
  const float* amax_t = (const float*)d_in[4];
  const float* Wu     = (const float*)d_in[5];
  const float* bu     = (const float*)d_in[6];
  const float* Wg     = (const float*)d_in[7];
  const float* bg     = (const float*)d_in[8];
  const float* Wa     = (const float*)d_in[9];
  const float* Wd     = (const float*)d_in[10];
  float* out = (float*)d_out;

  _Float16* wsB = (_Float16*)d_ws;  // 1024*512*2 = 1 MB

  pack_w<<<256, 256, 0, stream>>>(Wu, Wg, Wa, Wd, wsB);
  rwa_main<<<1024, 256, 0, stream>>>(x_t, n_t, d_t, h_t, amax_t, bu, bg, wsB, out);
}